// Round 1
// baseline (310.437 us; speedup 1.0000x reference)
//
#include <hip/hip_runtime.h>
#include <stdint.h>

#define NPTS 8192
#define NB   4
#define KNN  20
#define TILE 2048
#define WPB  8            // waves per block (one row per wave)
#define BLK  (WPB * 64)   // 512 threads
#define NROWS (NB * NPTS) // 32768
#define MTOT  (NB * NPTS * KNN)  // 655360 elements per channel for BN stats

__device__ __forceinline__ float med3f(float a, float b, float c) {
    return __builtin_amdgcn_fmed3f(a, b, c);
}

// K1: per row (b,n): find 20 smallest squared distances; emit
//   kmax = sqrt(d2_[19]), kmin = sqrt(d2_[0]), sum = sum sqrt(d2_i), sum2 = sum d2_i
__global__ __launch_bounds__(BLK) void knn_kernel(
    const float* __restrict__ x,
    float* __restrict__ kmaxA, float* __restrict__ kminA,
    float* __restrict__ rowS,  float* __restrict__ rowS2)
{
    // first 3*TILE floats reused for point tile; full 10240 floats for merge dump
    __shared__ float lds[BLK * KNN];   // 40 KB

    const int tid  = threadIdx.x;
    const int lane = tid & 63;
    const int wave = tid >> 6;
    const int rowBase = blockIdx.x * WPB;
    const int row  = rowBase + wave;
    const int b    = rowBase >> 13;          // blocks never span batches (1024 blocks/batch)
    const int n    = row & (NPTS - 1);
    const float* xb = x + b * 3 * NPTS;

    const float px = xb[n];
    const float py = xb[NPTS + n];
    const float pz = xb[2 * NPTS + n];

    float arr[KNN];                           // ascending squared distances
#pragma unroll
    for (int j = 0; j < KNN; ++j) arr[j] = 3.0e38f;

    for (int t = 0; t < NPTS; t += TILE) {
        __syncthreads();
#pragma unroll
        for (int i = tid; i < TILE; i += BLK) {
            lds[i]            = xb[t + i];
            lds[TILE + i]     = xb[NPTS + t + i];
            lds[2 * TILE + i] = xb[2 * NPTS + t + i];
        }
        __syncthreads();
        for (int i = lane; i < TILE; i += 64) {
            float dx = px - lds[i];
            float dy = py - lds[TILE + i];
            float dz = pz - lds[2 * TILE + i];
            float d2 = dx * dx;
            d2 = fmaf(dy, dy, d2);
            d2 = fmaf(dz, dz, d2);
            // branchless sorted-insert-drop-largest: 19x v_med3 + 1x v_min.
            // med3(d, lo, hi) with lo<=hi: d<lo -> lo (shift), lo<=d<=hi -> d (insert), d>hi -> hi (keep)
#pragma unroll
            for (int j = KNN - 1; j > 0; --j) arr[j] = med3f(d2, arr[j - 1], arr[j]);
            arr[0] = fminf(arr[0], d2);
        }
    }
    __syncthreads();

    // dump per-lane sorted lists to LDS, then 20 global extractions per wave
    float* my = lds + tid * KNN;
#pragma unroll
    for (int j = 0; j < KNN; ++j) my[j] = arr[j];
    __syncthreads();

    int pos = 0;
    float sum = 0.f, sum2 = 0.f, kmin = 0.f, kmax = 0.f;
    for (int kk = 0; kk < KNN; ++kk) {
        // head of my list (IEEE bits of non-negative float are order-monotone as u32)
        uint32_t bits = (pos < KNN) ? __float_as_uint(my[pos]) : 0x7f800000u;
        uint32_t mn = bits;
#pragma unroll
        for (int s = 32; s > 0; s >>= 1) {
            uint32_t o = (uint32_t)__shfl_xor((unsigned int)mn, s, 64);
            mn = (o < mn) ? o : mn;
        }
        unsigned long long msk = __ballot(bits == mn);
        int winner = (int)__builtin_ctzll(msk);   // one lane advances on ties
        if (lane == winner) pos++;
        float v2 = __uint_as_float(mn);
        float dv = sqrtf(v2);
        sum  += dv;
        sum2 += v2;
        if (kk == 0) kmin = dv;
        kmax = dv;                                 // last extraction = 20th smallest
    }
    if (lane == 0) {
        kmaxA[row] = kmax;
        kminA[row] = kmin;
        rowS[row]  = sum;
        rowS2[row] = sum2;
    }
}

// K2: reduce row partials -> mean/var -> per-channel a_c, d_c
__global__ __launch_bounds__(256) void stats_kernel(
    const float* __restrict__ rowS, const float* __restrict__ rowS2,
    const float* __restrict__ w, const float* __restrict__ cb,
    const float* __restrict__ gamma, const float* __restrict__ beta,
    float* __restrict__ ad)
{
    const int tid = threadIdx.x;
    float s = 0.f, s2 = 0.f;
    for (int i = tid; i < NROWS; i += 256) { s += rowS[i]; s2 += rowS2[i]; }
#pragma unroll
    for (int o = 32; o > 0; o >>= 1) {
        s  += __shfl_down(s, o, 64);
        s2 += __shfl_down(s2, o, 64);
    }
    __shared__ float ls[8];
    const int wave = tid >> 6, lane = tid & 63;
    if (lane == 0) { ls[wave] = s; ls[4 + wave] = s2; }
    __syncthreads();
    if (tid == 0) {
        float S  = ls[0] + ls[1] + ls[2] + ls[3];
        float S2 = ls[4] + ls[5] + ls[6] + ls[7];
        float mu  = S / (float)MTOT;
        float var = S2 / (float)MTOT - mu * mu;
        ls[0] = mu;
        ls[1] = var > 0.f ? var : 0.f;
    }
    __syncthreads();
    if (tid < 16) {
        float mu = ls[0], var = ls[1];
        float wc = w[tid];
        float ac = gamma[tid] * wc * rsqrtf(wc * wc * var + 1e-5f);
        ad[tid]      = ac;
        ad[16 + tid] = beta[tid] - ac * mu;   // note: conv bias cancels inside BN... 
        // wait: mean_c = w_c*mu + cb_c, feat - mean_c = w_c*(knn - mu); cb cancels exactly. ✓
        (void)cb;
    }
}

// K3: out[b,c,n] = lrelu(a_c * (a_c>=0 ? kmax : kmin) + d_c)
__global__ __launch_bounds__(256) void out_kernel(
    const float* __restrict__ kmaxA, const float* __restrict__ kminA,
    const float* __restrict__ ad, float* __restrict__ out)
{
    const int r = blockIdx.x * 256 + threadIdx.x;   // 0..32767
    const int b = r >> 13;
    const int n = r & (NPTS - 1);
    const float kmax = kmaxA[r];
    const float kmin = kminA[r];
#pragma unroll
    for (int c = 0; c < 16; ++c) {
        float a = ad[c];
        float d = ad[16 + c];
        float v = a * (a >= 0.f ? kmax : kmin) + d;
        v = (v >= 0.f) ? v : 0.2f * v;
        out[(b * 16 + c) * NPTS + n] = v;
    }
}

extern "C" void kernel_launch(void* const* d_in, const int* in_sizes, int n_in,
                              void* d_out, int out_size, void* d_ws, size_t ws_size,
                              hipStream_t stream)
{
    const float* x     = (const float*)d_in[0];
    const float* w     = (const float*)d_in[1];
    const float* cb    = (const float*)d_in[2];
    const float* gamma = (const float*)d_in[3];
    const float* beta  = (const float*)d_in[4];
    float* out = (float*)d_out;
    float* ws  = (float*)d_ws;

    float* kmaxA = ws;
    float* kminA = ws + NROWS;
    float* rowS  = ws + 2 * NROWS;
    float* rowS2 = ws + 3 * NROWS;
    float* ad    = ws + 4 * NROWS;   // 32 floats

    knn_kernel<<<NROWS / WPB, BLK, 0, stream>>>(x, kmaxA, kminA, rowS, rowS2);
    stats_kernel<<<1, 256, 0, stream>>>(rowS, rowS2, w, cb, gamma, beta, ad);
    out_kernel<<<NROWS / 256, 256, 0, stream>>>(kmaxA, kminA, ad, out);
}

// Round 2
// 272.653 us; speedup vs baseline: 1.1386x; 1.1386x over previous
//
#include <hip/hip_runtime.h>
#include <stdint.h>

#define NPTS  8192
#define NB    4
#define KNN   20
#define NROWS (NB * NPTS)        // 32768
#define MTOT  (NROWS * KNN)      // 655360 elements per channel for BN stats
#define TILE  2048               // candidates staged per tile
#define WPB   8                  // waves per block; all waves share the same 64 rows
#define BLK   (WPB * 64)         // 512 threads
#define SLICE (TILE / WPB)       // 256 candidates per wave per tile
#define LSTR  (KNN + 1)          // padded list stride (21) to spread LDS banks

__device__ __forceinline__ float med3f(float a, float b, float c) {
    return __builtin_amdgcn_fmed3f(a, b, c);
}

// K1: lane l owns row (blockIdx*64 + l). Each wave broadcasts candidates from
// LDS (uniform address -> HW broadcast, no LDS bandwidth) and maintains a
// per-lane descending top-20 list in t-space, t = p.q - |q|^2/2
// (d2 = |p|^2 - 2t, so larger t == smaller distance; med3 chain is order-agnostic).
__global__ __launch_bounds__(BLK) void knn_kernel(
    const float* __restrict__ x,
    float* __restrict__ kmaxA, float* __restrict__ kminA,
    float* __restrict__ rowS,  float* __restrict__ rowS2)
{
    __shared__ float4 tile[TILE];                 // 32 KB
    __shared__ float  lists[(WPB - 1) * 64 * LSTR]; // 7*64*21*4 = 37632 B

    const int tid  = threadIdx.x;
    const int lane = tid & 63;
    const int wave = tid >> 6;
    const int rowBase = blockIdx.x * 64;
    const int row  = rowBase + lane;
    const int b    = rowBase >> 13;          // 128 blocks per batch; blocks never span batches
    const int n    = row & (NPTS - 1);
    const float* xb = x + b * 3 * NPTS;

    const float px = xb[n];
    const float py = xb[NPTS + n];
    const float pz = xb[2 * NPTS + n];

    float arr[KNN];                          // descending t values (largest t = nearest)
#pragma unroll
    for (int j = 0; j < KNN; ++j) arr[j] = -3.0e38f;

    for (int t0 = 0; t0 < NPTS; t0 += TILE) {
        __syncthreads();
        // stage tile: (qx,qy,qz, -|q|^2/2), vectorized global loads
        {
            const int i4 = tid * 4;          // 512 threads * 4 = 2048 = TILE
            const float4 qx4 = *(const float4*)(xb + t0 + i4);
            const float4 qy4 = *(const float4*)(xb + NPTS + t0 + i4);
            const float4 qz4 = *(const float4*)(xb + 2 * NPTS + t0 + i4);
            tile[i4 + 0] = make_float4(qx4.x, qy4.x, qz4.x, -0.5f * (qx4.x*qx4.x + qy4.x*qy4.x + qz4.x*qz4.x));
            tile[i4 + 1] = make_float4(qx4.y, qy4.y, qz4.y, -0.5f * (qx4.y*qx4.y + qy4.y*qy4.y + qz4.y*qz4.y));
            tile[i4 + 2] = make_float4(qx4.z, qy4.z, qz4.z, -0.5f * (qx4.z*qx4.z + qy4.z*qy4.z + qz4.z*qz4.z));
            tile[i4 + 3] = make_float4(qx4.w, qy4.w, qz4.w, -0.5f * (qx4.w*qx4.w + qy4.w*qy4.w + qz4.w*qz4.w));
        }
        __syncthreads();

        const float4* base = tile + wave * SLICE;
#pragma unroll 4
        for (int i = 0; i < SLICE; ++i) {
            const float4 q = base[i];        // uniform address -> broadcast read
            float t = fmaf(q.x, px, fmaf(q.y, py, fmaf(q.z, pz, q.w)));
            // branchless insert-keep-largest-20: 19x med3 + 1x max
#pragma unroll
            for (int j = KNN - 1; j > 0; --j) arr[j] = med3f(t, arr[j - 1], arr[j]);
            arr[0] = fmaxf(arr[0], t);
        }
    }
    __syncthreads();

    // waves 1..7 dump their lists; wave 0 merges 7*20 values per lane
    if (wave > 0) {
        float* dst = lists + ((wave - 1) * 64 + lane) * LSTR;
#pragma unroll
        for (int j = 0; j < KNN; ++j) dst[j] = arr[j];
    }
    __syncthreads();

    if (wave == 0) {
        for (int wsrc = 0; wsrc < WPB - 1; ++wsrc) {
            const float* src = lists + (wsrc * 64 + lane) * LSTR;
#pragma unroll
            for (int k = 0; k < KNN; ++k) {
                const float t = src[k];
#pragma unroll
                for (int j = KNN - 1; j > 0; --j) arr[j] = med3f(t, arr[j - 1], arr[j]);
                arr[0] = fmaxf(arr[0], t);
            }
        }
        // finalize: convert t back to distances. arr[0]=nearest, arr[19]=20th.
        const float pn2 = px * px + py * py + pz * pz;
        float sum = 0.f, sum2 = 0.f, dmin = 0.f, dmax = 0.f;
#pragma unroll
        for (int k = 0; k < KNN; ++k) {
            float d2 = fmaf(-2.f, arr[k], pn2);
            d2 = fmaxf(d2, 0.f);             // clamp cancellation noise (ref clamps too)
            const float d = sqrtf(d2);
            sum  += d;
            sum2 += d2;
            if (k == 0) dmin = d;
            dmax = d;
        }
        kmaxA[row] = dmax;
        kminA[row] = dmin;
        rowS[row]  = sum;
        rowS2[row] = sum2;
    }
}

// K2: reduce row partials -> mean/var -> per-channel a_c, d_c
// (conv bias cancels inside BN: feat - mean_c = w_c*(knn - mu))
__global__ __launch_bounds__(256) void stats_kernel(
    const float* __restrict__ rowS, const float* __restrict__ rowS2,
    const float* __restrict__ w, const float* __restrict__ cb,
    const float* __restrict__ gamma, const float* __restrict__ beta,
    float* __restrict__ ad)
{
    const int tid = threadIdx.x;
    float s = 0.f, s2 = 0.f;
    for (int i = tid; i < NROWS; i += 256) { s += rowS[i]; s2 += rowS2[i]; }
#pragma unroll
    for (int o = 32; o > 0; o >>= 1) {
        s  += __shfl_down(s, o, 64);
        s2 += __shfl_down(s2, o, 64);
    }
    __shared__ float ls[8];
    const int wave = tid >> 6, lane = tid & 63;
    if (lane == 0) { ls[wave] = s; ls[4 + wave] = s2; }
    __syncthreads();
    if (tid == 0) {
        float S  = ls[0] + ls[1] + ls[2] + ls[3];
        float S2 = ls[4] + ls[5] + ls[6] + ls[7];
        float mu  = S / (float)MTOT;
        float var = S2 / (float)MTOT - mu * mu;
        ls[0] = mu;
        ls[1] = var > 0.f ? var : 0.f;
    }
    __syncthreads();
    if (tid < 16) {
        float mu = ls[0], var = ls[1];
        float wc = w[tid];
        float ac = gamma[tid] * wc * rsqrtf(wc * wc * var + 1e-5f);
        ad[tid]      = ac;
        ad[16 + tid] = beta[tid] - ac * mu;
        (void)cb;
    }
}

// K3: out[b,c,n] = lrelu(a_c * (a_c>=0 ? kmax : kmin) + d_c)
__global__ __launch_bounds__(256) void out_kernel(
    const float* __restrict__ kmaxA, const float* __restrict__ kminA,
    const float* __restrict__ ad, float* __restrict__ out)
{
    const int r = blockIdx.x * 256 + threadIdx.x;   // 0..32767
    const int b = r >> 13;
    const int n = r & (NPTS - 1);
    const float kmax = kmaxA[r];
    const float kmin = kminA[r];
#pragma unroll
    for (int c = 0; c < 16; ++c) {
        float a = ad[c];
        float d = ad[16 + c];
        float v = a * (a >= 0.f ? kmax : kmin) + d;
        v = (v >= 0.f) ? v : 0.2f * v;
        out[(b * 16 + c) * NPTS + n] = v;
    }
}

extern "C" void kernel_launch(void* const* d_in, const int* in_sizes, int n_in,
                              void* d_out, int out_size, void* d_ws, size_t ws_size,
                              hipStream_t stream)
{
    const float* x     = (const float*)d_in[0];
    const float* w     = (const float*)d_in[1];
    const float* cb    = (const float*)d_in[2];
    const float* gamma = (const float*)d_in[3];
    const float* beta  = (const float*)d_in[4];
    float* out = (float*)d_out;
    float* ws  = (float*)d_ws;

    float* kmaxA = ws;
    float* kminA = ws + NROWS;
    float* rowS  = ws + 2 * NROWS;
    float* rowS2 = ws + 3 * NROWS;
    float* ad    = ws + 4 * NROWS;   // 32 floats

    knn_kernel<<<NROWS / 64, BLK, 0, stream>>>(x, kmaxA, kminA, rowS, rowS2);
    stats_kernel<<<1, 256, 0, stream>>>(rowS, rowS2, w, cb, gamma, beta, ad);
    out_kernel<<<NROWS / 256, 256, 0, stream>>>(kmaxA, kminA, ad, out);
}

// Round 3
// 252.017 us; speedup vs baseline: 1.2318x; 1.0819x over previous
//
#include <hip/hip_runtime.h>
#include <stdint.h>

#define NPTS  8192
#define NB    4
#define KNN   20
#define NROWS (NB * NPTS)        // 32768
#define MTOTF 655360.0f          // NROWS * KNN
#define WPB   8                  // waves per block; all waves share the same 64 rows
#define BLK   (WPB * 64)         // 512 threads
#define SLICE (NPTS / WPB)       // 1024 candidates per wave
#define LSTR  (KNN + 1)          // padded merge-list stride
#define NEG_INF -3.0e38f

__device__ __forceinline__ float med3f(float a, float b, float c) {
    return __builtin_amdgcn_fmed3f(a, b, c);
}

// Shared tail: wave 0 holds the merged descending-t list for row `row`.
// t = p.q - |q|^2/2, d2 = |p|^2 - 2t  (arr[0] = largest t = nearest).
__device__ __forceinline__ void finalize_row(
    float arr[KNN], float px, float py, float pz, int row, int lane,
    float* __restrict__ kmaxA, float* __restrict__ kminA, float* __restrict__ acc)
{
    const float pn2 = px * px + py * py + pz * pz;
    float sum = 0.f, sum2 = 0.f, dmin = 0.f, dmax = 0.f;
#pragma unroll
    for (int k = 0; k < KNN; ++k) {
        float d2 = fmaxf(fmaf(-2.f, arr[k], pn2), 0.f);
        float d = sqrtf(d2);
        sum += d; sum2 += d2;
        if (k == 0) dmin = d;
        dmax = d;
    }
    kmaxA[row] = dmax;
    kminA[row] = dmin;
#pragma unroll
    for (int o = 32; o; o >>= 1) {
        sum  += __shfl_down(sum,  o, 64);
        sum2 += __shfl_down(sum2, o, 64);
    }
    if (lane == 0) { atomicAdd(acc, sum); atomicAdd(acc + 1, sum2); }
}

// Prep: tile4[b*NPTS+m] = (qx, qy, qz, -|q|^2/2); zero the stats accumulator.
__global__ __launch_bounds__(256) void prep_kernel(
    const float* __restrict__ x, float4* __restrict__ tile4, float* __restrict__ acc)
{
    const int i = blockIdx.x * 256 + threadIdx.x;    // 0..32767
    const int b = i >> 13;
    const int m = i & (NPTS - 1);
    const float* xb = x + b * 3 * NPTS;
    const float qx = xb[m], qy = xb[NPTS + m], qz = xb[2 * NPTS + m];
    tile4[i] = make_float4(qx, qy, qz, -0.5f * (qx * qx + qy * qy + qz * qz));
    if (i < 2) acc[i] = 0.f;
}

// K1 (main): lane = row, candidates streamed through the SCALAR pipe
// (wave-uniform address -> s_load / uniform vector load; no LDS in hot loop).
__global__ __launch_bounds__(BLK, 8) void knn_kernel(
    const float* __restrict__ x, const float4* __restrict__ tile4,
    float* __restrict__ kmaxA, float* __restrict__ kminA, float* __restrict__ acc)
{
    __shared__ float lists[(WPB - 1) * 64 * LSTR];   // 37632 B -> 4 blocks/CU

    const int tid  = threadIdx.x;
    const int lane = tid & 63;
    const int wave = __builtin_amdgcn_readfirstlane(tid >> 6);
    const int rowBase = blockIdx.x * 64;
    const int row  = rowBase + lane;
    const int b    = rowBase >> 13;          // 128 blocks per batch
    const int n    = row & (NPTS - 1);
    const float* xb = x + b * 3 * NPTS;

    const float px = xb[n];
    const float py = xb[NPTS + n];
    const float pz = xb[2 * NPTS + n];

    float arr[KNN];
#pragma unroll
    for (int j = 0; j < KNN; ++j) arr[j] = NEG_INF;

    const float4* __restrict__ tp = tile4 + b * NPTS + wave * SLICE;
#pragma unroll 8
    for (int i = 0; i < SLICE; ++i) {
        const float4 q = tp[i];              // wave-uniform -> scalar load
        float t = fmaf(q.x, px, fmaf(q.y, py, fmaf(q.z, pz, q.w)));
#pragma unroll
        for (int j = KNN - 1; j > 0; --j) arr[j] = med3f(t, arr[j - 1], arr[j]);
        arr[0] = fmaxf(arr[0], t);
    }

    if (wave > 0) {
        float* dst = lists + ((wave - 1) * 64 + lane) * LSTR;
#pragma unroll
        for (int j = 0; j < KNN; ++j) dst[j] = arr[j];
    }
    __syncthreads();

    if (wave == 0) {
        for (int wsrc = 0; wsrc < WPB - 1; ++wsrc) {
            const float* src = lists + (wsrc * 64 + lane) * LSTR;
#pragma unroll
            for (int k = 0; k < KNN; ++k) {
                const float t = src[k];
#pragma unroll
                for (int j = KNN - 1; j > 0; --j) arr[j] = med3f(t, arr[j - 1], arr[j]);
                arr[0] = fmaxf(arr[0], t);
            }
        }
        finalize_row(arr, px, py, pz, row, lane, kmaxA, kminA, acc);
    }
}

// K1 (fallback, round-2 structure): used only if ws_size can't hold the tile.
__global__ __launch_bounds__(BLK) void knn_kernel_lds(
    const float* __restrict__ x,
    float* __restrict__ kmaxA, float* __restrict__ kminA, float* __restrict__ acc)
{
    __shared__ float4 tile[2048];
    __shared__ float  lists[(WPB - 1) * 64 * LSTR];

    const int tid  = threadIdx.x;
    const int lane = tid & 63;
    const int wave = tid >> 6;
    const int rowBase = blockIdx.x * 64;
    const int row  = rowBase + lane;
    const int b    = rowBase >> 13;
    const int n    = row & (NPTS - 1);
    const float* xb = x + b * 3 * NPTS;

    const float px = xb[n];
    const float py = xb[NPTS + n];
    const float pz = xb[2 * NPTS + n];

    float arr[KNN];
#pragma unroll
    for (int j = 0; j < KNN; ++j) arr[j] = NEG_INF;

    for (int t0 = 0; t0 < NPTS; t0 += 2048) {
        __syncthreads();
        const int i4 = tid * 4;
        const float4 qx4 = *(const float4*)(xb + t0 + i4);
        const float4 qy4 = *(const float4*)(xb + NPTS + t0 + i4);
        const float4 qz4 = *(const float4*)(xb + 2 * NPTS + t0 + i4);
        tile[i4 + 0] = make_float4(qx4.x, qy4.x, qz4.x, -0.5f * (qx4.x*qx4.x + qy4.x*qy4.x + qz4.x*qz4.x));
        tile[i4 + 1] = make_float4(qx4.y, qy4.y, qz4.y, -0.5f * (qx4.y*qx4.y + qy4.y*qy4.y + qz4.y*qz4.y));
        tile[i4 + 2] = make_float4(qx4.z, qy4.z, qz4.z, -0.5f * (qx4.z*qx4.z + qy4.z*qy4.z + qz4.z*qz4.z));
        tile[i4 + 3] = make_float4(qx4.w, qy4.w, qz4.w, -0.5f * (qx4.w*qx4.w + qy4.w*qy4.w + qz4.w*qz4.w));
        __syncthreads();
        const float4* base = tile + wave * 256;
#pragma unroll 4
        for (int i = 0; i < 256; ++i) {
            const float4 q = base[i];
            float t = fmaf(q.x, px, fmaf(q.y, py, fmaf(q.z, pz, q.w)));
#pragma unroll
            for (int j = KNN - 1; j > 0; --j) arr[j] = med3f(t, arr[j - 1], arr[j]);
            arr[0] = fmaxf(arr[0], t);
        }
    }
    __syncthreads();

    if (wave > 0) {
        float* dst = lists + ((wave - 1) * 64 + lane) * LSTR;
#pragma unroll
        for (int j = 0; j < KNN; ++j) dst[j] = arr[j];
    }
    __syncthreads();

    if (wave == 0) {
        for (int wsrc = 0; wsrc < WPB - 1; ++wsrc) {
            const float* src = lists + (wsrc * 64 + lane) * LSTR;
#pragma unroll
            for (int k = 0; k < KNN; ++k) {
                const float t = src[k];
#pragma unroll
                for (int j = KNN - 1; j > 0; --j) arr[j] = med3f(t, arr[j - 1], arr[j]);
                arr[0] = fmaxf(arr[0], t);
            }
        }
        finalize_row(arr, px, py, pz, row, lane, kmaxA, kminA, acc);
    }
}

// K2: per-thread BN-coefficient computation (16 rsqrt, trivial) + output.
// out[b,c,n] = lrelu(a_c * (a_c>=0 ? kmax : kmin) + d_c)
__global__ __launch_bounds__(256) void out_kernel(
    const float* __restrict__ kmaxA, const float* __restrict__ kminA,
    const float* __restrict__ acc,
    const float* __restrict__ w, const float* __restrict__ gamma,
    const float* __restrict__ beta, float* __restrict__ out)
{
    const int r = blockIdx.x * 256 + threadIdx.x;   // 0..32767
    const int b = r >> 13;
    const int n = r & (NPTS - 1);
    const float mu  = acc[0] * (1.0f / MTOTF);
    float var = acc[1] * (1.0f / MTOTF) - mu * mu;
    var = fmaxf(var, 0.f);
    const float kmax = kmaxA[r];
    const float kmin = kminA[r];
#pragma unroll
    for (int c = 0; c < 16; ++c) {
        const float wc = w[c];
        const float a = gamma[c] * wc * rsqrtf(wc * wc * var + 1e-5f);
        const float d = beta[c] - a * mu;     // conv bias cancels inside BN
        float v = a * (a >= 0.f ? kmax : kmin) + d;
        v = (v >= 0.f) ? v : 0.2f * v;
        out[(b * 16 + c) * NPTS + n] = v;
    }
}

extern "C" void kernel_launch(void* const* d_in, const int* in_sizes, int n_in,
                              void* d_out, int out_size, void* d_ws, size_t ws_size,
                              hipStream_t stream)
{
    const float* x     = (const float*)d_in[0];
    const float* w     = (const float*)d_in[1];
    const float* gamma = (const float*)d_in[3];
    const float* beta  = (const float*)d_in[4];
    float* out = (float*)d_out;
    float* ws  = (float*)d_ws;

    float* kmaxA = ws;                       // NROWS floats
    float* kminA = ws + NROWS;               // NROWS floats
    float* acc   = ws + 2 * NROWS;           // 2 floats
    // tile at 16B-aligned float offset 2*NROWS+4
    float4* tile4 = (float4*)(ws + 2 * NROWS + 4);
    const size_t need = (size_t)(2 * NROWS + 4) * 4 + (size_t)NROWS * 16;

    if (ws_size >= need) {
        prep_kernel<<<NROWS / 256, 256, 0, stream>>>(x, tile4, acc);
        knn_kernel<<<NROWS / 64, BLK, 0, stream>>>(x, tile4, kmaxA, kminA, acc);
    } else {
        prep_kernel<<<1, 256, 0, stream>>>(x, tile4, acc);      // only zeroes acc via i<2... 
        knn_kernel_lds<<<NROWS / 64, BLK, 0, stream>>>(x, kmaxA, kminA, acc);
    }
    out_kernel<<<NROWS / 256, 256, 0, stream>>>(kmaxA, kminA, acc, w, gamma, beta, out);
}